// Round 6
// baseline (135.108 us; speedup 1.0000x reference)
//
#include <hip/hip_runtime.h>
#include <hip/hip_fp16.h>

#define G 64

typedef float        v4f __attribute__((ext_vector_type(4)));
typedef int          v4i __attribute__((ext_vector_type(4)));
typedef unsigned int v4u __attribute__((ext_vector_type(4)));
typedef unsigned int   u32;
typedef unsigned short u16;

__device__ __forceinline__ v4f nt_load_f4(const float* p) {
    return __builtin_nontemporal_load((const v4f*)p);
}
__device__ __forceinline__ v4i nt_load_i4(const int* p) {
    return __builtin_nontemporal_load((const v4i*)p);
}

__global__ void zero_out_kernel(float* out) {
    if (threadIdx.x == 0 && blockIdx.x == 0) out[0] = 0.0f;
}

// ---- Corner-packed grid table: ctab[cell] = 8 fp16 corners (16B) ----
// order: g000,g001,g010,g011,g100,g101,g110,g111 (x:bit2, y:bit1, z:bit0)
__global__ __launch_bounds__(256) void build_ctab_kernel(
    const float* __restrict__ grid, v4f* __restrict__ ctab)
{
    int idx = blockIdx.x * blockDim.x + threadIdx.x;
    if (idx >= G * G * G) return;
    int z = idx & 63, y = (idx >> 6) & 63, x = idx >> 12;
    int xp = min(x + 1, 63), yp = min(y + 1, 63), zp = min(z + 1, 63);

    float g000 = grid[(x  * G + y ) * G + z ];
    float g001 = grid[(x  * G + y ) * G + zp];
    float g010 = grid[(x  * G + yp) * G + z ];
    float g011 = grid[(x  * G + yp) * G + zp];
    float g100 = grid[(xp * G + y ) * G + z ];
    float g101 = grid[(xp * G + y ) * G + zp];
    float g110 = grid[(xp * G + yp) * G + z ];
    float g111 = grid[(xp * G + yp) * G + zp];

    __half2 h01 = __floats2half2_rn(g000, g001);
    __half2 h23 = __floats2half2_rn(g010, g011);
    __half2 h45 = __floats2half2_rn(g100, g101);
    __half2 h67 = __floats2half2_rn(g110, g111);

    union { __half2 h[4]; v4f v; } u;
    u.h[0] = h01; u.h[1] = h23; u.h[2] = h45; u.h[3] = h67;
    ctab[idx] = u.v;
}

__device__ __forceinline__ float trilinear_sq_packed(const v4f* __restrict__ ctab,
                                                     float x, float y, float z)
{
    float px = x * 63.0f, py = y * 63.0f, pz = z * 63.0f;
    int x0 = min(max((int)floorf(px), 0), 62);
    int y0 = min(max((int)floorf(py), 0), 62);
    int z0 = min(max((int)floorf(pz), 0), 62);
    float fx = px - (float)x0;
    float fy = py - (float)y0;
    float fz = pz - (float)z0;

    union { v4f v; __half2 h[4]; } u;
    u.v = ctab[(x0 * G + y0) * G + z0];   // one 16B gather
    float2 f01 = __half22float2(u.h[0]);  // g000,g001
    float2 f23 = __half22float2(u.h[1]);  // g010,g011
    float2 f45 = __half22float2(u.h[2]);  // g100,g101
    float2 f67 = __half22float2(u.h[3]);  // g110,g111

    float c00 = f01.x + (f45.x - f01.x) * fx;
    float c01 = f01.y + (f45.y - f01.y) * fx;
    float c10 = f23.x + (f67.x - f23.x) * fx;
    float c11 = f23.y + (f67.y - f23.y) * fx;
    float c0  = c00 + (c10 - c00) * fy;
    float c1  = c01 + (c11 - c01) * fy;
    float d   = c0 + (c1 - c0) * fz;
    return 0.5f * d * d;
}

// pack coord -> u16: x:5 | y:6 | z:5
__device__ __forceinline__ u32 quant565(float x, float y, float z) {
    u32 ux = (u32)(fmaf(x, 31.0f, 0.5f));
    u32 uy = (u32)(fmaf(y, 63.0f, 0.5f));
    u32 uz = (u32)(fmaf(z, 31.0f, 0.5f));
    return ux | (uy << 5) | (uz << 11);
}

// Fused: quantize V into Vq AND accumulate part-1 trilinear loss.
// 8 points / iteration: 6 float4 V-loads, 8 independent ctab gathers.
__global__ __launch_bounds__(256) void quant_tri_kernel(
    const float* __restrict__ V, v4u* __restrict__ Vq128,
    const v4f* __restrict__ ctab, float* __restrict__ out, int N)
{
    const int tid    = blockIdx.x * blockDim.x + threadIdx.x;
    const int stride = gridDim.x * blockDim.x;
    float acc = 0.0f;

    for (int base = tid * 8; base < N; base += stride * 8) {
        if (base + 8 <= N) {
            v4f c[6];
            #pragma unroll
            for (int k = 0; k < 6; ++k) c[k] = nt_load_f4(V + base*3 + 4*k);
            const float* f = (const float*)c;
            u32 q[8];
            #pragma unroll
            for (int k = 0; k < 8; ++k) {
                float x = f[3*k], y = f[3*k+1], z = f[3*k+2];
                acc += trilinear_sq_packed(ctab, x, y, z);
                q[k] = quant565(x, y, z);
            }
            v4u w = { q[0] | (q[1] << 16), q[2] | (q[3] << 16),
                      q[4] | (q[5] << 16), q[6] | (q[7] << 16) };
            __builtin_nontemporal_store(w, Vq128 + (base >> 3));
        } else {
            u16* Vq = (u16*)Vq128;
            for (int i = base; i < N; ++i) {
                float x = V[3*i], y = V[3*i+1], z = V[3*i+2];
                acc += trilinear_sq_packed(ctab, x, y, z);
                Vq[i] = (u16)quant565(x, y, z);
            }
        }
    }

    for (int off = 32; off > 0; off >>= 1)
        acc += __shfl_down(acc, off, 64);
    __shared__ float wsum[4];
    const int lane = threadIdx.x & 63;
    const int wid  = threadIdx.x >> 6;
    if (lane == 0) wsum[wid] = acc;
    __syncthreads();
    if (threadIdx.x == 0)
        atomicAdd(out, wsum[0] + wsum[1] + wsum[2] + wsum[3]);
}

__device__ __forceinline__ float edge_loss_q(u32 a, u32 b, float r)
{
    const float i31 = 1.0f / 31.0f;
    const float i63 = 1.0f / 63.0f;
    float ax = (float)(a & 31u) * i31;
    float ay = (float)((a >> 5) & 63u) * i63;
    float az = (float)((a >> 11) & 31u) * i31;
    float bx = (float)(b & 31u) * i31;
    float by = (float)((b >> 5) & 63u) * i63;
    float bz = (float)((b >> 11) & 31u) * i31;
    float dx = ax - bx, dy = ay - by, dz = az - bz;
    float elen = sqrtf(dx*dx + dy*dy + dz*dz + 1e-12f);
    float t = elen - r;
    return 0.5f * t * t;
}

// 16 edges / iteration: 32 independent 2B gathers in flight.
__global__ __launch_bounds__(256) void edge_kernel(
    const u16*   __restrict__ Vq,    // [N] quantized, 4MB table
    const int*   __restrict__ E,     // [NE,2] int32 flat
    const float* __restrict__ rest,  // [NE]
    float* __restrict__ out, int NE)
{
    const int tid    = blockIdx.x * blockDim.x + threadIdx.x;
    const int stride = gridDim.x * blockDim.x;
    float acc = 0.0f;

    for (int base = tid * 16; base < NE; base += stride * 16) {
        if (base + 16 <= NE) {
            v4i e[8];
            v4f r[4];
            #pragma unroll
            for (int k = 0; k < 8; ++k) e[k] = nt_load_i4(E + base*2 + 4*k);
            #pragma unroll
            for (int k = 0; k < 4; ++k) r[k] = nt_load_f4(rest + base + 4*k);

            u32 a[16], b[16];
            #pragma unroll
            for (int k = 0; k < 8; ++k) {
                a[2*k]   = Vq[e[k].x];
                b[2*k]   = Vq[e[k].y];
                a[2*k+1] = Vq[e[k].z];
                b[2*k+1] = Vq[e[k].w];
            }
            const float* rr = (const float*)r;
            #pragma unroll
            for (int k = 0; k < 16; ++k)
                acc += edge_loss_q(a[k], b[k], rr[k]);
        } else {
            for (int i = base; i < NE; ++i)
                acc += edge_loss_q(Vq[E[2*i]], Vq[E[2*i+1]], rest[i]);
        }
    }

    for (int off = 32; off > 0; off >>= 1)
        acc += __shfl_down(acc, off, 64);
    __shared__ float wsum[4];
    const int lane = threadIdx.x & 63;
    const int wid  = threadIdx.x >> 6;
    if (lane == 0) wsum[wid] = acc;
    __syncthreads();
    if (threadIdx.x == 0)
        atomicAdd(out, wsum[0] + wsum[1] + wsum[2] + wsum[3]);
}

extern "C" void kernel_launch(void* const* d_in, const int* in_sizes, int n_in,
                              void* d_out, int out_size, void* d_ws, size_t ws_size,
                              hipStream_t stream) {
    const float* V    = (const float*)d_in[0];   // src_V  [N,3]
    // d_in[1] = src_F (unused by the reference)
    const int*   E    = (const int*)d_in[2];     // src_E  [NE,2] int32
    const float* grid = (const float*)d_in[3];   // dist_grid [64,64,64]
    const float* rest = (const float*)d_in[4];   // rest_len [NE]
    float* out = (float*)d_out;

    const int N  = in_sizes[0] / 3;
    const int NE = in_sizes[2] / 2;

    zero_out_kernel<<<1, 64, 0, stream>>>(out);

    // ws layout: [0, 2N) bytes = Vq (u16/vertex, 4MB) ; then ctab (4MB, 16B-aligned)
    char* ws = (char*)d_ws;
    v4u* Vq128 = (v4u*)ws;
    size_t vq_bytes = ((size_t)N * 2 + 255) & ~(size_t)255;
    v4f* ctab = (v4f*)(ws + vq_bytes);

    build_ctab_kernel<<<(G*G*G + 255) / 256, 256, 0, stream>>>(grid, ctab);

    const int block = 256;
    const int grid_blocks = 2048;
    quant_tri_kernel<<<grid_blocks, block, 0, stream>>>(V, Vq128, ctab, out, N);
    edge_kernel<<<grid_blocks, block, 0, stream>>>(
        (const u16*)Vq128, E, rest, out, NE);
}

// Round 7
// 119.245 us; speedup vs baseline: 1.1330x; 1.1330x over previous
//
#include <hip/hip_runtime.h>
#include <hip/hip_fp16.h>

#define G 64

typedef float        v4f __attribute__((ext_vector_type(4)));
typedef int          v4i __attribute__((ext_vector_type(4)));
typedef unsigned int v4u __attribute__((ext_vector_type(4)));
typedef unsigned int   u32;
typedef unsigned short u16;

__device__ __forceinline__ v4f nt_load_f4(const float* p) {
    return __builtin_nontemporal_load((const v4f*)p);
}
__device__ __forceinline__ v4i nt_load_i4(const int* p) {
    return __builtin_nontemporal_load((const v4i*)p);
}

__global__ void zero_out_kernel(float* out) {
    if (threadIdx.x == 0 && blockIdx.x == 0) out[0] = 0.0f;
}

// ---- Corner-packed grid table: ctab[cell] = 8 fp16 corners (16B) ----
__global__ __launch_bounds__(256) void build_ctab_kernel(
    const float* __restrict__ grid, v4f* __restrict__ ctab)
{
    int idx = blockIdx.x * blockDim.x + threadIdx.x;
    if (idx >= G * G * G) return;
    int z = idx & 63, y = (idx >> 6) & 63, x = idx >> 12;
    int xp = min(x + 1, 63), yp = min(y + 1, 63), zp = min(z + 1, 63);

    float g000 = grid[(x  * G + y ) * G + z ];
    float g001 = grid[(x  * G + y ) * G + zp];
    float g010 = grid[(x  * G + yp) * G + z ];
    float g011 = grid[(x  * G + yp) * G + zp];
    float g100 = grid[(xp * G + y ) * G + z ];
    float g101 = grid[(xp * G + y ) * G + zp];
    float g110 = grid[(xp * G + yp) * G + z ];
    float g111 = grid[(xp * G + yp) * G + zp];

    union { __half2 h[4]; v4f v; } u;
    u.h[0] = __floats2half2_rn(g000, g001);
    u.h[1] = __floats2half2_rn(g010, g011);
    u.h[2] = __floats2half2_rn(g100, g101);
    u.h[3] = __floats2half2_rn(g110, g111);
    ctab[idx] = u.v;
}

__device__ __forceinline__ float trilinear_sq_packed(const v4f* __restrict__ ctab,
                                                     float x, float y, float z)
{
    float px = x * 63.0f, py = y * 63.0f, pz = z * 63.0f;
    int x0 = min(max((int)floorf(px), 0), 62);
    int y0 = min(max((int)floorf(py), 0), 62);
    int z0 = min(max((int)floorf(pz), 0), 62);
    float fx = px - (float)x0;
    float fy = py - (float)y0;
    float fz = pz - (float)z0;

    union { v4f v; __half2 h[4]; } u;
    u.v = ctab[(x0 * G + y0) * G + z0];   // one 16B gather
    float2 f01 = __half22float2(u.h[0]);  // g000,g001
    float2 f23 = __half22float2(u.h[1]);  // g010,g011
    float2 f45 = __half22float2(u.h[2]);  // g100,g101
    float2 f67 = __half22float2(u.h[3]);  // g110,g111

    float c00 = f01.x + (f45.x - f01.x) * fx;
    float c01 = f01.y + (f45.y - f01.y) * fx;
    float c10 = f23.x + (f67.x - f23.x) * fx;
    float c11 = f23.y + (f67.y - f23.y) * fx;
    float c0  = c00 + (c10 - c00) * fy;
    float c1  = c01 + (c11 - c01) * fy;
    float d   = c0 + (c1 - c0) * fz;
    return 0.5f * d * d;
}

// pack coord -> u16: x:5 | y:6 | z:5
__device__ __forceinline__ u32 quant565(float x, float y, float z) {
    u32 ux = (u32)(fmaf(x, 31.0f, 0.5f));
    u32 uy = (u32)(fmaf(y, 63.0f, 0.5f));
    u32 uz = (u32)(fmaf(z, 31.0f, 0.5f));
    return ux | (uy << 5) | (uz << 11);
}

// Fused: quantize V into Vq AND accumulate part-1 trilinear loss.
// 4 points / thread, exact-fit grid (no multi-iteration imbalance).
__global__ __launch_bounds__(256) void quant_tri_kernel(
    const float* __restrict__ V, uint2* __restrict__ Vq64,
    const v4f* __restrict__ ctab, float* __restrict__ out, int N)
{
    const int tid  = blockIdx.x * blockDim.x + threadIdx.x;
    const int base = tid * 4;
    float acc = 0.0f;

    if (base + 4 <= N) {
        v4f c0 = nt_load_f4(V + base*3);
        v4f c1 = nt_load_f4(V + base*3 + 4);
        v4f c2 = nt_load_f4(V + base*3 + 8);
        float xs[4] = {c0.x, c0.w, c1.z, c2.y};
        float ys[4] = {c0.y, c1.x, c1.w, c2.z};
        float zs[4] = {c0.z, c1.y, c2.x, c2.w};
        u32 q[4];
        #pragma unroll
        for (int k = 0; k < 4; ++k) {
            acc += trilinear_sq_packed(ctab, xs[k], ys[k], zs[k]);
            q[k] = quant565(xs[k], ys[k], zs[k]);
        }
        Vq64[base >> 2] = make_uint2(q[0] | (q[1] << 16), q[2] | (q[3] << 16));
    } else if (base < N) {
        u16* Vq = (u16*)Vq64;
        for (int i = base; i < N; ++i) {
            float x = V[3*i], y = V[3*i+1], z = V[3*i+2];
            acc += trilinear_sq_packed(ctab, x, y, z);
            Vq[i] = (u16)quant565(x, y, z);
        }
    }

    for (int off = 32; off > 0; off >>= 1)
        acc += __shfl_down(acc, off, 64);
    __shared__ float wsum[4];
    const int lane = threadIdx.x & 63;
    const int wid  = threadIdx.x >> 6;
    if (lane == 0) wsum[wid] = acc;
    __syncthreads();
    if (threadIdx.x == 0)
        atomicAdd(out, wsum[0] + wsum[1] + wsum[2] + wsum[3]);
}

__device__ __forceinline__ float edge_loss_q(u32 a, u32 b, float r)
{
    const float i31 = 1.0f / 31.0f;
    const float i63 = 1.0f / 63.0f;
    float ax = (float)(a & 31u) * i31;
    float ay = (float)((a >> 5) & 63u) * i63;
    float az = (float)((a >> 11) & 31u) * i31;
    float bx = (float)(b & 31u) * i31;
    float by = (float)((b >> 5) & 63u) * i63;
    float bz = (float)((b >> 11) & 31u) * i31;
    float dx = ax - bx, dy = ay - by, dz = az - bz;
    float elen = sqrtf(dx*dx + dy*dy + dz*dz + 1e-12f);
    float t = elen - r;
    return 0.5f * t * t;
}

// 8 edges / thread, exact-fit grid: 16 gathers in flight, low VGPR.
__global__ __launch_bounds__(256) void edge_kernel(
    const u16*   __restrict__ Vq,    // [N] quantized, 4MB table
    const int*   __restrict__ E,     // [NE,2] int32 flat
    const float* __restrict__ rest,  // [NE]
    float* __restrict__ out, int NE)
{
    const int tid  = blockIdx.x * blockDim.x + threadIdx.x;
    const int base = tid * 8;
    float acc = 0.0f;

    if (base + 8 <= NE) {
        v4i e0 = nt_load_i4(E + base*2);
        v4i e1 = nt_load_i4(E + base*2 + 4);
        v4i e2 = nt_load_i4(E + base*2 + 8);
        v4i e3 = nt_load_i4(E + base*2 + 12);
        v4f r0 = nt_load_f4(rest + base);
        v4f r1 = nt_load_f4(rest + base + 4);

        u32 a0 = Vq[e0.x], b0 = Vq[e0.y];
        u32 a1 = Vq[e0.z], b1 = Vq[e0.w];
        u32 a2 = Vq[e1.x], b2 = Vq[e1.y];
        u32 a3 = Vq[e1.z], b3 = Vq[e1.w];
        u32 a4 = Vq[e2.x], b4 = Vq[e2.y];
        u32 a5 = Vq[e2.z], b5 = Vq[e2.w];
        u32 a6 = Vq[e3.x], b6 = Vq[e3.y];
        u32 a7 = Vq[e3.z], b7 = Vq[e3.w];

        acc += edge_loss_q(a0, b0, r0.x);
        acc += edge_loss_q(a1, b1, r0.y);
        acc += edge_loss_q(a2, b2, r0.z);
        acc += edge_loss_q(a3, b3, r0.w);
        acc += edge_loss_q(a4, b4, r1.x);
        acc += edge_loss_q(a5, b5, r1.y);
        acc += edge_loss_q(a6, b6, r1.z);
        acc += edge_loss_q(a7, b7, r1.w);
    } else if (base < NE) {
        for (int i = base; i < NE; ++i)
            acc += edge_loss_q(Vq[E[2*i]], Vq[E[2*i+1]], rest[i]);
    }

    for (int off = 32; off > 0; off >>= 1)
        acc += __shfl_down(acc, off, 64);
    __shared__ float wsum[4];
    const int lane = threadIdx.x & 63;
    const int wid  = threadIdx.x >> 6;
    if (lane == 0) wsum[wid] = acc;
    __syncthreads();
    if (threadIdx.x == 0)
        atomicAdd(out, wsum[0] + wsum[1] + wsum[2] + wsum[3]);
}

extern "C" void kernel_launch(void* const* d_in, const int* in_sizes, int n_in,
                              void* d_out, int out_size, void* d_ws, size_t ws_size,
                              hipStream_t stream) {
    const float* V    = (const float*)d_in[0];   // src_V  [N,3]
    // d_in[1] = src_F (unused by the reference)
    const int*   E    = (const int*)d_in[2];     // src_E  [NE,2] int32
    const float* grid = (const float*)d_in[3];   // dist_grid [64,64,64]
    const float* rest = (const float*)d_in[4];   // rest_len [NE]
    float* out = (float*)d_out;

    const int N  = in_sizes[0] / 3;
    const int NE = in_sizes[2] / 2;

    zero_out_kernel<<<1, 64, 0, stream>>>(out);

    // ws layout: Vq (u16/vertex, 4MB) then ctab (4MB, 16B-aligned)
    char* ws = (char*)d_ws;
    uint2* Vq64 = (uint2*)ws;
    size_t vq_bytes = ((size_t)N * 2 + 255) & ~(size_t)255;
    v4f* ctab = (v4f*)(ws + vq_bytes);

    build_ctab_kernel<<<(G*G*G + 255) / 256, 256, 0, stream>>>(grid, ctab);

    // Exact-fit grids: one iteration per thread, no multi-iter imbalance.
    const int block = 256;
    const int quant_blocks = (N  + block*4 - 1) / (block*4);  // 4 pts/thread
    const int edge_blocks  = (NE + block*8 - 1) / (block*8);  // 8 edges/thread

    quant_tri_kernel<<<quant_blocks, block, 0, stream>>>(V, Vq64, ctab, out, N);
    edge_kernel<<<edge_blocks, block, 0, stream>>>(
        (const u16*)Vq64, E, rest, out, NE);
}